// Round 12
// baseline (1309.101 us; speedup 1.0000x reference)
//
#include <hip/hip_runtime.h>
#include <stdint.h>

typedef unsigned short ushort_t;
typedef __attribute__((ext_vector_type(8))) short short8;
typedef __attribute__((ext_vector_type(4))) float f32x4;

#define DEVINL __device__ __forceinline__

DEVINL ushort_t f2bf(float f){
  union { float f; uint32_t u; } v; v.f = f;
  uint32_t u = v.u;
  uint32_t r = (u + 0x7fffu + ((u >> 16) & 1u)) >> 16;
  return (ushort_t)r;
}
DEVINL float bf2f(ushort_t h){
  union { uint32_t u; float f; } v; v.u = ((uint32_t)h) << 16;
  return v.f;
}
DEVINL f32x4 mfma16(short8 a, short8 b, f32x4 c){
  return __builtin_amdgcn_mfma_f32_16x16x32_bf16(a, b, c, 0, 0, 0);
}
DEVINL void gload_lds16(const void* g, void* l){
  __builtin_amdgcn_global_load_lds((const __attribute__((address_space(1))) void*)g,
                                   (__attribute__((address_space(3))) void*)l, 16, 0, 0);
}
DEVINL float gelu_tanh(float x){
  return 0.5f * x * (1.f + tanhf(0.7978845608028654f * (x + 0.044715f * x * x * x)));
}

#define BAR() __builtin_amdgcn_s_barrier()
#define LGK0() asm volatile("s_waitcnt lgkmcnt(0)" ::: "memory")
#define VMC4() asm volatile("s_waitcnt vmcnt(4)" ::: "memory")
#define VMC0() asm volatile("s_waitcnt vmcnt(0)" ::: "memory")
#define PRIO1() __builtin_amdgcn_s_setprio(1)
#define PRIO0() __builtin_amdgcn_s_setprio(0)

// ---------------------------------------------------------------------------
// Transpose + fp32->bf16: W[K][N] -> Wt[N][K]
// ---------------------------------------------------------------------------
__global__ void transpose_bf16(const float* __restrict__ W, ushort_t* __restrict__ Wt,
                               int K, int N)
{
  __shared__ ushort_t tile[64 * 65];
  const int t = threadIdx.x;
  const int k0 = blockIdx.y * 64, n0 = blockIdx.x * 64;
#pragma unroll
  for (int rr = 0; rr < 4; ++rr){
    const int row = rr * 16 + (t >> 4);
    const int c4 = (t & 15) * 4;
    float4 v = *(const float4*)&W[(size_t)(k0 + row) * N + n0 + c4];
    ushort_t* dst = &tile[row * 65 + c4];
    dst[0] = f2bf(v.x); dst[1] = f2bf(v.y); dst[2] = f2bf(v.z); dst[3] = f2bf(v.w);
  }
  __syncthreads();
  const int n = t >> 2, kc = (t & 3) * 16;
  __align__(16) ushort_t tmp[16];
#pragma unroll
  for (int j = 0; j < 16; ++j) tmp[j] = tile[(kc + j) * 65 + n];
  ushort_t* out = &Wt[(size_t)(n0 + n) * K + k0 + kc];
  *(short8*)&out[0] = *(short8*)&tmp[0];
  *(short8*)&out[8] = *(short8*)&tmp[8];
}

// ---------------------------------------------------------------------------
// mod1/mod2 = adarms_cond @ e_adaX_w + e_adaX_b   (tiny GEMV)
// ---------------------------------------------------------------------------
__global__ void mod_kernel(const float* __restrict__ cond,
                           const float* __restrict__ w1, const float* __restrict__ b1,
                           const float* __restrict__ w2, const float* __restrict__ b2,
                           float* __restrict__ mod1, float* __restrict__ mod2)
{
  __shared__ float cs[1024];
  const int bid = blockIdx.x, tid = threadIdx.x;
  const int which = bid / 48, rem = bid % 48, b = rem / 12, j0 = (rem % 12) * 256;
  const float* W = which ? w2 : w1;
  const float* bias = which ? b2 : b1;
  float* out = which ? mod2 : mod1;
#pragma unroll
  for (int i = 0; i < 4; ++i) cs[i * 256 + tid] = cond[b * 1024 + i * 256 + tid];
  __syncthreads();
  const int j = j0 + tid;
  float acc = bias[j];
  for (int k = 0; k < 1024; ++k) acc = fmaf(cs[k], W[(size_t)k * 3072 + j], acc);
  out[b * 3072 + j] = acc;
}

// ---------------------------------------------------------------------------
// RMSNorm -> bf16
// ---------------------------------------------------------------------------
__global__ void rms_kernel(const float* __restrict__ x, ushort_t* __restrict__ out, int D,
                           const float* __restrict__ sw, const float* __restrict__ sh,
                           int mod_rpb, int mod_stride)
{
  const int row = blockIdx.x, tid = threadIdx.x;
  const float* xr = x + (size_t)row * D;
  const int nc = D >> 10;
  float ss = 0.f;
  for (int c = 0; c < nc; ++c){
    float4 v = *(const float4*)&xr[c * 1024 + tid * 4];
    ss += v.x * v.x + v.y * v.y + v.z * v.z + v.w * v.w;
  }
  for (int o = 32; o > 0; o >>= 1) ss += __shfl_xor(ss, o);
  __shared__ float red[4];
  if ((tid & 63) == 0) red[tid >> 6] = ss;
  __syncthreads();
  const float scale = rsqrtf((red[0] + red[1] + red[2] + red[3]) / (float)D + 1e-6f);
  const float* swp = sw;
  const float* shp = sh;
  if (mod_rpb){
    int bb = row / mod_rpb;
    swp += (size_t)bb * mod_stride;
    if (shp) shp += (size_t)bb * mod_stride;
  }
  for (int c = 0; c < nc; ++c){
    const int d = c * 1024 + tid * 4;
    float4 v = *(const float4*)&xr[d];
    float vv[4] = {v.x, v.y, v.z, v.w};
#pragma unroll
    for (int i = 0; i < 4; ++i){
      float tv = vv[i] * scale * (1.f + swp[d + i]);
      if (shp) tv += shp[d + i];
      out[(size_t)row * D + d + i] = f2bf(tv);
    }
  }
}

// ---------------------------------------------------------------------------
// RoPE + layout.  K and V stored with 16B-chunk XOR permutation inside each
// 64-token tile (conflict-free attn LDS reads; both-sides rule).
// ---------------------------------------------------------------------------
__global__ void rope_kernel(const ushort_t* __restrict__ qkv_p, const ushort_t* __restrict__ qkv_e,
                            const int* __restrict__ pos_ids,
                            ushort_t* __restrict__ q_all, ushort_t* __restrict__ k_all,
                            ushort_t* __restrict__ vT)
{
  const int tok = blockIdx.x, tid = threadIdx.x;
  int b, s;
  const ushort_t* src;
  if (tok < 3072){ b = tok / 768; s = tok - b * 768; src = qkv_p + (size_t)tok * 2560; }
  else { int te = tok - 3072; b = te >> 6; s = 768 + (te & 63); src = qkv_e + (size_t)te * 2560; }
  const int pos = pos_ids[b * 832 + s];
  __shared__ float cs[128], sn[128];
  if (tid < 128){
    float f = powf(10000.f, -(float)tid * (1.f / 128.f));
    float a = (float)pos * f;
    cs[tid] = cosf(a); sn[tid] = sinf(a);
  }
  __syncthreads();
#pragma unroll
  for (int c = 0; c < 10; ++c){
    const int n = c * 256 + tid;
    const float v = bf2f(src[n]);
    if (n < 2048){
      const int h = n >> 8, d = n & 255;
      const float o = bf2f(src[(h << 8) + ((d < 128) ? (d + 128) : (d - 128))]);
      const int dd = d & 127;
      const float r = (d < 128) ? v * cs[dd] - o * sn[dd] : v * cs[dd] + o * sn[dd];
      q_all[(((size_t)(b * 8 + h)) * 832 + s) * 256 + d] = f2bf(r);
    } else if (n < 2304){
      const int d = n - 2048;
      const float o = bf2f(src[2048 + ((d < 128) ? (d + 128) : (d - 128))]);
      const int dd = d & 127;
      const float r = (d < 128) ? v * cs[dd] - o * sn[dd] : v * cs[dd] + o * sn[dd];
      const int ck = d >> 3, e = d & 7;
      const int ck2 = ck ^ (s & 7);
      k_all[((size_t)(b * 832) + s) * 256 + (ck2 << 3) + e] = f2bf(r);
    } else {
      const int d = n - 2304;
      const int stile = s >> 6, sl = s & 63;
      const int cv = sl >> 3, e = sl & 7;
      const int cv2 = cv ^ (d & 7);
      vT[((size_t)(b * 256) + d) * 832 + (stile << 6) + (cv2 << 3) + e] = src[n];
    }
  }
}

// ---------------------------------------------------------------------------
// Flash attention (K/V chunk-deswizzle on ds_read)
// ---------------------------------------------------------------------------
__global__ void __launch_bounds__(256, 2)
attn_kernel(const ushort_t* __restrict__ q_all, const ushort_t* __restrict__ k_all,
            const ushort_t* __restrict__ vT, const float* __restrict__ mask,
            ushort_t* __restrict__ att)
{
  __shared__ __align__(16) ushort_t Ks[64 * 256];
  __shared__ __align__(16) ushort_t Vs[256 * 64];
  __shared__ __align__(16) ushort_t Ps[4][16 * 72];
  const int tid = threadIdx.x, lane = tid & 63, wid = tid >> 6;
  const int l15 = lane & 15, lg = lane >> 4;
  const int qt = blockIdx.x, h = blockIdx.y, b = blockIdx.z;
  const int q0 = qt * 64 + wid * 16;
  const int x7 = l15 & 7;

  short8 qf[8];
  {
    const ushort_t* qr = q_all + (((size_t)(b * 8 + h) * 832) + q0 + l15) * 256;
#pragma unroll
    for (int s = 0; s < 8; ++s) qf[s] = *(const short8*)&qr[s * 32 + lg * 8];
  }

  f32x4 accO[16] = {};
  float mrow[4] = {-3.0e38f, -3.0e38f, -3.0e38f, -3.0e38f};
  float lrow[4] = {0.f, 0.f, 0.f, 0.f};

  for (int kt = 0; kt < 13; ++kt){
    const int s0 = kt * 64;
#pragma unroll
    for (int i = 0; i < 8; ++i){
      const int o = i * 256 + tid;
      gload_lds16(k_all + ((size_t)(b * 832) + s0 + (o >> 5)) * 256 + (o & 31) * 8, &Ks[o * 8]);
      gload_lds16(vT + ((size_t)(b * 256) + (o >> 3)) * 832 + s0 + (o & 7) * 8, &Vs[o * 8]);
    }
    __syncthreads();

    f32x4 sc[4] = {};
#pragma unroll
    for (int s = 0; s < 8; ++s){
#pragma unroll
      for (int nf = 0; nf < 4; ++nf){
        short8 kb = *(const short8*)&Ks[(nf * 16 + l15) * 256 + (((s * 4 + lg) ^ x7) << 3)];
        sc[nf] = mfma16(qf[s], kb, sc[nf]);
      }
    }
#pragma unroll
    for (int nf = 0; nf < 4; ++nf){
#pragma unroll
      for (int r = 0; r < 4; ++r){
        const int q = q0 + lg * 4 + r;
        const int kk = s0 + nf * 16 + l15;
        sc[nf][r] = sc[nf][r] * 0.0625f + mask[((size_t)b * 832 + q) * 832 + kk];
      }
    }
    float al[4];
#pragma unroll
    for (int r = 0; r < 4; ++r){
      float tm = fmaxf(fmaxf(sc[0][r], sc[1][r]), fmaxf(sc[2][r], sc[3][r]));
      tm = fmaxf(tm, __shfl_xor(tm, 1));
      tm = fmaxf(tm, __shfl_xor(tm, 2));
      tm = fmaxf(tm, __shfl_xor(tm, 4));
      tm = fmaxf(tm, __shfl_xor(tm, 8));
      const float mnew = fmaxf(mrow[r], tm);
      al[r] = __expf(mrow[r] - mnew);
      mrow[r] = mnew;
      float rs = 0.f;
#pragma unroll
      for (int nf = 0; nf < 4; ++nf){
        const float p = __expf(sc[nf][r] - mnew);
        rs += p;
        Ps[wid][(lg * 4 + r) * 72 + nf * 16 + l15] = f2bf(p);
      }
      rs += __shfl_xor(rs, 1);
      rs += __shfl_xor(rs, 2);
      rs += __shfl_xor(rs, 4);
      rs += __shfl_xor(rs, 8);
      lrow[r] = lrow[r] * al[r] + rs;
    }
#pragma unroll
    for (int nd = 0; nd < 16; ++nd){
#pragma unroll
      for (int r = 0; r < 4; ++r) accO[nd][r] *= al[r];
    }
#pragma unroll
    for (int ks = 0; ks < 2; ++ks){
      short8 pa = *(const short8*)&Ps[wid][l15 * 72 + ks * 32 + lg * 8];
#pragma unroll
      for (int nd = 0; nd < 16; ++nd){
        short8 vb = *(const short8*)&Vs[(nd * 16 + l15) * 64 + (((ks * 4 + lg) ^ x7) << 3)];
        accO[nd] = mfma16(pa, vb, accO[nd]);
      }
    }
    __syncthreads();
  }
#pragma unroll
  for (int nd = 0; nd < 16; ++nd){
#pragma unroll
    for (int r = 0; r < 4; ++r){
      const int q = q0 + lg * 4 + r;
      const int d = nd * 16 + l15;
      att[((size_t)(b * 832) + q) * 2048 + h * 256 + d] = f2bf(accO[nd][r] / lrow[r]);
    }
  }
}

// ---------------------------------------------------------------------------
// 128x128 2-phase GEMM (proven) + n-strip bijective XCD decode
// ---------------------------------------------------------------------------
template<int EPI>
__global__ void __launch_bounds__(256, 2)
gemm_bt(const ushort_t* __restrict__ A, int lda, int a_rpb, int a_bstride, int a_r0,
        const ushort_t* __restrict__ Bt, int ldb,
        void* __restrict__ Cv, int N, int K,
        const void* __restrict__ Xv,
        const float* __restrict__ gatep, int gate_stride, int gate_rpb,
        size_t pstride)
{
  __shared__ __align__(16) ushort_t As[128 * 64];
  __shared__ __align__(16) ushort_t Bs[128 * 64];
  const int tid = threadIdx.x;
  const int lane = tid & 63;
  const int l15 = lane & 15, lg = lane >> 4;
  const int wid = tid >> 6;
  const int wm = (wid >> 1) * 64, wn = (wid & 1) * 64;
  const int gx = gridDim.x, gy = gridDim.y, nwg = gx * gy;
  const int orig = blockIdx.y * gx + blockIdx.x;
  const int q = nwg >> 3, r = nwg & 7;
  const int xcd = orig & 7, lo = orig >> 3;
  const int wg = (xcd < r ? xcd * (q + 1) : r * (q + 1) + (xcd - r) * q) + lo;
  const int m0 = (wg % gy) * 128, n0 = (wg / gy) * 128;
  const int z = blockIdx.z;
  const int kbeg = z * K, kend = z * K + K;

  size_t abase[4], bbase[4];
  const int k8 = (tid & 7) * 8;
#pragma unroll
  for (int i = 0; i < 4; ++i){
    const int row = (i * 256 + tid) >> 3;
    const int rr = m0 + row;
    const int bb = rr / a_rpb;
    const int arow = bb * a_bstride + a_r0 + (rr - bb * a_rpb);
    abase[i] = (size_t)arow * lda + k8;
    bbase[i] = (size_t)(n0 + row) * ldb + k8;
  }

  f32x4 acc[4][4] = {};

  for (int kt = kbeg; kt < kend; kt += 64){
#pragma unroll
    for (int i = 0; i < 4; ++i){
      gload_lds16(A + abase[i] + kt, &As[(i * 256 + tid) * 8]);
      gload_lds16(Bt + bbase[i] + kt, &Bs[(i * 256 + tid) * 8]);
    }
    __syncthreads();
#pragma unroll
    for (int s = 0; s < 2; ++s){
      const int ko = s * 32 + lg * 8;
      short8 af[4], bfr[4];
#pragma unroll
      for (int i = 0; i < 4; ++i) af[i] = *(const short8*)&As[(wm + i * 16 + l15) * 64 + ko];
#pragma unroll
      for (int j = 0; j < 4; ++j) bfr[j] = *(const short8*)&Bs[(wn + j * 16 + l15) * 64 + ko];
#pragma unroll
      for (int i = 0; i < 4; ++i)
#pragma unroll
        for (int j = 0; j < 4; ++j)
          acc[i][j] = mfma16(af[i], bfr[j], acc[i][j]);
    }
    __syncthreads();
  }

#pragma unroll
  for (int i = 0; i < 4; ++i){
#pragma unroll
    for (int rr = 0; rr < 4; ++rr){
      const int m = m0 + wm + i * 16 + lg * 4 + rr;
#pragma unroll
      for (int j = 0; j < 4; ++j){
        const int n = n0 + wn + j * 16 + l15;
        const size_t idx = (size_t)m * N + n;
        const float v = acc[i][j][rr];
        if (EPI == 0){
          ((ushort_t*)Cv)[idx] = f2bf(v);
        } else if (EPI == 1){
          const float g = bf2f(((const ushort_t*)Xv)[idx]);
          ((ushort_t*)Cv)[idx] = f2bf(gelu_tanh(g) * v);
        } else if (EPI == 2){
          ((float*)Cv)[idx] = ((const float*)Xv)[idx] + v;
        } else if (EPI == 3){
          const int bb = m / gate_rpb;
          ((float*)Cv)[idx] = ((const float*)Xv)[idx] + gatep[(size_t)bb * gate_stride + n] * v;
        } else {
          ((float*)Cv)[(size_t)z * pstride + idx] = v;
        }
      }
    }
  }
}

// ---------------------------------------------------------------------------
// 256x256 GEMM, 2 phases per K-tile, hoisted addresses, n-strip XCD mapping
// (used for the prefix down split-K)
// ---------------------------------------------------------------------------
#define MMAQ(AF, BF, MQ, NQ) \
  { _Pragma("unroll") for (int i_ = 0; i_ < 4; ++i_){ \
      _Pragma("unroll") for (int j_ = 0; j_ < 2; ++j_){ \
        _Pragma("unroll") for (int s_ = 0; s_ < 2; ++s_){ \
          acc[(MQ)*4 + i_][(NQ)*2 + j_] = \
            mfma16(AF[i_][s_], BF[j_][s_], acc[(MQ)*4 + i_][(NQ)*2 + j_]); } } } }

#define READA(F, BUF, OA) \
  { _Pragma("unroll") for (int i_ = 0; i_ < 4; ++i_){ \
      _Pragma("unroll") for (int s_ = 0; s_ < 2; ++s_){ \
        F[i_][s_] = *(const short8*)&(BUF)[OA[i_][s_]]; } } }

#define READB(F, BUF, OB) \
  { _Pragma("unroll") for (int j_ = 0; j_ < 2; ++j_){ \
      _Pragma("unroll") for (int s_ = 0; s_ < 2; ++s_){ \
        F[j_][s_] = *(const short8*)&(BUF)[OB[j_][s_]]; } } }

template<int EPI>
__global__ void __launch_bounds__(512, 1)
gemm8(const ushort_t* __restrict__ A, int lda,
      const ushort_t* __restrict__ Bt, int ldb,
      void* __restrict__ Cv, int N, int klen,
      const void* __restrict__ Xv, size_t pstride)
{
  __shared__ __align__(16) ushort_t As[2][256 * 64];
  __shared__ __align__(16) ushort_t Bs[2][256 * 64];

  const int tid = threadIdx.x;
  const int lane = tid & 63, wid = tid >> 6;
  const int l15 = lane & 15, lg = lane >> 4;
  const int wm = (wid >> 2) * 128, wn = (wid & 3) * 64;

  const int gx = gridDim.x, gy = gridDim.y, nwg = gx * gy;
  const int orig = blockIdx.y * gx + blockIdx.x;
  const int q = nwg >> 3, r = nwg & 7;
  const int xcd = orig & 7, lo = orig >> 3;
  const int wg = (xcd < r ? xcd * (q + 1) : r * (q + 1) + (xcd - r) * q) + lo;
  const int m0 = (wg % gy) * 256, n0 = (wg / gy) * 256;
  const int z = blockIdx.z;
  const size_t k0 = (size_t)z * klen;
  const int NT = klen >> 6;

  uint32_t offA0[4][2], offA1[4][2], offB0[2][2], offB1[2][2];
#pragma unroll
  for (int i = 0; i < 4; ++i){
#pragma unroll
    for (int s = 0; s < 2; ++s){
      int r0 = wm + 0 * 64 + i * 16 + l15;
      int r1 = wm + 1 * 64 + i * 16 + l15;
      offA0[i][s] = r0 * 64 + (((s * 4 + lg) ^ (r0 & 7)) << 3);
      offA1[i][s] = r1 * 64 + (((s * 4 + lg) ^ (r1 & 7)) << 3);
    }
  }
#pragma unroll
  for (int j = 0; j < 2; ++j){
#pragma unroll
    for (int s = 0; s < 2; ++s){
      int r0 = wn + 0 * 32 + j * 16 + l15;
      int r1 = wn + 1 * 32 + j * 16 + l15;
      offB0[j][s] = r0 * 64 + (((s * 4 + lg) ^ (r0 & 7)) << 3);
      offB1[j][s] = r1 * 64 + (((s * 4 + lg) ^ (r1 & 7)) << 3);
    }
  }

  const ushort_t* gptr[4][2];
  uint32_t ldso[2];
#pragma unroll
  for (int c = 0; c < 2; ++c){
    const int idx = c * 512 + tid;
    const int row = idx >> 3, slot = idx & 7;
    const uint32_t sw = (uint32_t)((slot ^ (row & 7)) << 3);
    ldso[c] = (uint32_t)idx * 8;
    gptr[0][c] = A  + (size_t)(m0 + row) * lda + k0 + sw;
    gptr[1][c] = A  + (size_t)(m0 + 128 + row) * lda + k0 + sw;
    gptr[2][c] = Bt + (size_t)(n0 + row) * ldb + k0 + sw;
    gptr[3][c] = Bt + (size_t)(n0 + 128 + row) * ldb + k0 + sw;
  }

  auto stage = [&](int buf, int half, int kt){
    ushort_t* base = (half < 2) ? &As[buf][(half & 1) * 8192] : &Bs[buf][(half & 1) * 8192];
#pragma unroll
    for (int c = 0; c < 2; ++c)
      gload_lds16(gptr[half][c] + kt, base + ldso[c]);
  };

  stage(0, 0, 0); stage(0, 1, 0); stage(0, 2, 0); stage(0, 3, 0);
  if (NT > 1){ stage(1, 2, 64); stage(1, 3, 64); VMC4(); } else { VMC0(); }
  BAR();

  short8 af[4][2], bq0[2][2], bq1[2][2];
  f32x4 acc[8][4] = {};

  for (int t = 0; t < NT; ++t){
    const int cur = t & 1, nxt = cur ^ 1;
    const int kc1 = (t + 1) << 6, kc2 = (t + 2) << 6;
    const ushort_t* Ac = As[cur];
    const ushort_t* Bc = Bs[cur];
    READA(af, Ac, offA0);
    READB(bq0, Bc, offB0);
    READB(bq1, Bc, offB1);
    if (t + 1 < NT){ stage(nxt, 0, kc1); stage(nxt, 1, kc1); }
    BAR(); LGK0();
    PRIO1(); MMAQ(af, bq0, 0, 0); MMAQ(af, bq1, 0, 1); PRIO0(); BAR();
    READA(af, Ac, offA1);
    if (t + 2 < NT){ stage(cur, 2, kc2); stage(cur, 3, kc2); VMC4(); } else { VMC0(); }
    BAR(); LGK0();
    PRIO1(); MMAQ(af, bq1, 1, 1); MMAQ(af, bq0, 1, 0); PRIO0(); BAR();
  }

#pragma unroll
  for (int i = 0; i < 8; ++i){
#pragma unroll
    for (int rr = 0; rr < 4; ++rr){
      const int m = m0 + wm + i * 16 + lg * 4 + rr;
#pragma unroll
      for (int j = 0; j < 4; ++j){
        const int n = n0 + wn + j * 16 + l15;
        const size_t idx = (size_t)m * N + n;
        const float v = acc[i][j][rr];
        if (EPI == 0){
          ((ushort_t*)Cv)[idx] = f2bf(v);
        } else if (EPI == 1){
          const float g = bf2f(((const ushort_t*)Xv)[idx]);
          ((ushort_t*)Cv)[idx] = f2bf(gelu_tanh(g) * v);
        } else {
          ((float*)Cv)[(size_t)z * pstride + idx] = v;
        }
      }
    }
  }
}

// out = res + sum_{z<4} part[z]   (prefix down reduce)
__global__ void reduce4(const float* __restrict__ part, const float* __restrict__ res,
                        float* __restrict__ out, int total4, size_t pstride)
{
  int i = blockIdx.x * blockDim.x + threadIdx.x;
  const int stride = gridDim.x * blockDim.x;
  for (; i < total4; i += stride){
    const size_t e = (size_t)i * 4;
    float4 a = *(const float4*)&res[e];
#pragma unroll
    for (int z = 0; z < 4; ++z){
      float4 p = *(const float4*)&part[(size_t)z * pstride + e];
      a.x += p.x; a.y += p.y; a.z += p.z; a.w += p.w;
    }
    *(float4*)&out[e] = a;
  }
}

// g_out[row][n] = bf16( gelu(sum_z P[z][row][n]) * sum_z P[z][row][4096+n] )
// P rows 8192 wide (gate|up halves); nz=4.
__global__ void fuse_gelu(const float* __restrict__ P, ushort_t* __restrict__ out,
                          int total4, size_t zstride)
{
  int i = blockIdx.x * blockDim.x + threadIdx.x;
  const int stride = gridDim.x * blockDim.x;
  for (; i < total4; i += stride){
    const size_t e = (size_t)i * 4;
    const int row = (int)(e >> 12);
    const int n   = (int)(e & 4095);
    const size_t gb = (size_t)row * 8192 + n;
    float4 g = *(const float4*)&P[gb];
    float4 u = *(const float4*)&P[gb + 4096];
#pragma unroll
    for (int z = 1; z < 4; ++z){
      float4 a = *(const float4*)&P[(size_t)z * zstride + gb];
      float4 b = *(const float4*)&P[(size_t)z * zstride + gb + 4096];
      g.x += a.x; g.y += a.y; g.z += a.z; g.w += a.w;
      u.x += b.x; u.y += b.y; u.z += b.z; u.w += b.w;
    }
    out[e + 0] = f2bf(gelu_tanh(g.x) * u.x);
    out[e + 1] = f2bf(gelu_tanh(g.y) * u.y);
    out[e + 2] = f2bf(gelu_tanh(g.z) * u.z);
    out[e + 3] = f2bf(gelu_tanh(g.w) * u.w);
  }
}

// out = base + gate[b][n] * sum_{z<nz} part[z]
__global__ void reduce_gated(const float* __restrict__ part, size_t pstride, int nz,
                             const float* __restrict__ base, const float* __restrict__ gate,
                             int gstride, int rpb, int N,
                             float* __restrict__ out, int total4)
{
  int i = blockIdx.x * blockDim.x + threadIdx.x;
  const int stride = gridDim.x * blockDim.x;
  for (; i < total4; i += stride){
    const size_t e = (size_t)i * 4;
    const int row = (int)(e / N), n = (int)(e % N);
    const int b = row / rpb;
    float4 s = *(const float4*)&part[e];
    for (int z = 1; z < nz; ++z){
      float4 p = *(const float4*)&part[(size_t)z * pstride + e];
      s.x += p.x; s.y += p.y; s.z += p.z; s.w += p.w;
    }
    float4 bs = *(const float4*)&base[e];
    const float* gp = &gate[(size_t)b * gstride + n];
    bs.x += gp[0] * s.x; bs.y += gp[1] * s.y; bs.z += gp[2] * s.z; bs.w += gp[3] * s.w;
    *(float4*)&out[e] = bs;
  }
}

// ---------------------------------------------------------------------------
extern "C" void kernel_launch(void* const* d_in, const int* in_sizes, int n_in,
                              void* d_out, int out_size, void* d_ws, size_t ws_size,
                              hipStream_t stream)
{
  const float* x_prefix = (const float*)d_in[0];
  const float* x_expert = (const float*)d_in[1];
  const float* mask     = (const float*)d_in[2];
  const float* cond     = (const float*)d_in[3];
  const int*   pos      = (const int*)d_in[4];
  const float* p_ln1    = (const float*)d_in[5];
  const float* p_wq     = (const float*)d_in[6];
  const float* p_wk     = (const float*)d_in[7];
  const float* p_wv     = (const float*)d_in[8];
  const float* p_wo     = (const float*)d_in[9];
  const float* p_ln2    = (const float*)d_in[10];
  const float* p_wgate  = (const float*)d_in[11];
  const float* p_wup    = (const float*)d_in[12];
  const float* p_wdown  = (const float*)d_in[13];
  const float* e_ada1_w = (const float*)d_in[14];
  const float* e_ada1_b = (const float*)d_in[15];
  const float* e_wq     = (const float*)d_in[16];
  const float* e_wk     = (const float*)d_in[17];
  const float* e_wv     = (const float*)d_in[18];
  const float* e_wo     = (const float*)d_in[19];
  const float* e_ada2_w = (const float*)d_in[20];
  const float* e_ada2_b = (const float*)d_in[21];
  const float* e_wgate  = (const float*)d_in[22];
  const float* e_wup    = (const float*)d_in[23];
  const float* e_wdown  = (const float*)d_in[24];

  char* ws = (char*)d_ws;
  size_t off = 0;
  auto alloc = [&](size_t bytes) -> char* {
    char* p = ws + off;
    off += bytes;
    off = (off + 255) & ~(size_t)255;
    return p;
  };

  ushort_t* t_wqkv_p  = (ushort_t*)alloc((size_t)2560 * 2048 * 2);
  ushort_t* t_wo_p    = (ushort_t*)alloc((size_t)2048 * 2048 * 2);
  ushort_t* t_wgate_p = (ushort_t*)alloc((size_t)16384 * 2048 * 2);
  ushort_t* t_wup_p   = (ushort_t*)alloc((size_t)16384 * 2048 * 2);
  ushort_t* t_wdown_p = (ushort_t*)alloc((size_t)2048 * 16384 * 2);
  ushort_t* t_wqkv_e  = (ushort_t*)alloc((size_t)2560 * 1024 * 2);
  ushort_t* t_wo_e    = (ushort_t*)alloc((size_t)1024 * 2048 * 2);
  ushort_t* t_wgate_e = (ushort_t*)alloc((size_t)4096 * 1024 * 2);  // contiguous with wup_e
  ushort_t* t_wup_e   = (ushort_t*)alloc((size_t)4096 * 1024 * 2);
  ushort_t* t_wdown_e = (ushort_t*)alloc((size_t)1024 * 4096 * 2);
  float* mod1 = (float*)alloc((size_t)4 * 3072 * 4);
  float* mod2 = (float*)alloc((size_t)4 * 3072 * 4);
  float* res_p = (float*)alloc((size_t)3072 * 2048 * 4);
  float* res_e = (float*)alloc((size_t)256 * 1024 * 4);
  ushort_t* h2_p = (ushort_t*)alloc((size_t)3072 * 2048 * 2);
  ushort_t* h2_e = (ushort_t*)alloc((size_t)256 * 1024 * 2);
  ushort_t* g_e  = (ushort_t*)alloc((size_t)256 * 4096 * 2);

  const size_t zone_off = off;
  ushort_t* h_p   = (ushort_t*)alloc((size_t)3072 * 2048 * 2);
  ushort_t* h_e   = (ushort_t*)alloc((size_t)256 * 1024 * 2);
  ushort_t* qkv_p = (ushort_t*)alloc((size_t)3072 * 2560 * 2);
  ushort_t* qkv_e = (ushort_t*)alloc((size_t)256 * 2560 * 2);
  ushort_t* q_all = (ushort_t*)alloc((size_t)4 * 8 * 832 * 256 * 2);
  ushort_t* k_all = (ushort_t*)alloc((size_t)4 * 832 * 256 * 2);
  ushort_t* vTb   = (ushort_t*)alloc((size_t)4 * 256 * 832 * 2);
  ushort_t* att   = (ushort_t*)alloc((size_t)4 * 832 * 2048 * 2);
  const size_t phase1_end = off;
  ushort_t* g_p = (ushort_t*)(ws + zone_off); // [3072][16384] bf16, MLP phase only

  // overlays (stream-ordered):
  float* partials = (float*)t_wgate_p;           // prefix down partials [4][3072][2048]
  const size_t PSTRIDE_P = (size_t)3072 * 2048;
  float* pwo = (float*)(ws + zone_off);          // e-wo partials over h_p
  const size_t PSTRIDE_E = (size_t)256 * 1024;
  float* pgu = (float*)t_wgate_p;                // expert merged gate|up partials [4][256][8192]
  const size_t PSTRIDE_GU = (size_t)256 * 8192;
  float* pd = pgu + (size_t)4 * PSTRIDE_GU;      // expert down partials [8][256][1024]

  const size_t g_p_end = zone_off + (size_t)3072 * 16384 * 2;
  const size_t needed = (phase1_end > g_p_end) ? phase1_end : g_p_end;
  if (ws_size < needed) return;

  const int BIG = 1 << 30;

  // 1) weight transposes
  transpose_bf16<<<dim3(2048/64, 2048/64), 256, 0, stream>>>(p_wq, t_wqkv_p, 2048, 2048);
  transpose_bf16<<<dim3(256/64, 2048/64), 256, 0, stream>>>(p_wk, t_wqkv_p + (size_t)2048*2048, 2048, 256);
  transpose_bf16<<<dim3(256/64, 2048/64), 256, 0, stream>>>(p_wv, t_wqkv_p + (size_t)2304*2048, 2048, 256);
  transpose_bf16<<<dim3(2048/64, 2048/64), 256, 0, stream>>>(p_wo, t_wo_p, 2048, 2048);
  transpose_bf16<<<dim3(16384/64, 2048/64), 256, 0, stream>>>(p_wgate, t_wgate_p, 2048, 16384);
  transpose_bf16<<<dim3(16384/64, 2048/64), 256, 0, stream>>>(p_wup, t_wup_p, 2048, 16384);
  transpose_bf16<<<dim3(2048/64, 16384/64), 256, 0, stream>>>(p_wdown, t_wdown_p, 16384, 2048);
  transpose_bf16<<<dim3(2048/64, 1024/64), 256, 0, stream>>>(e_wq, t_wqkv_e, 1024, 2048);
  transpose_bf16<<<dim3(256/64, 1024/64), 256, 0, stream>>>(e_wk, t_wqkv_e + (size_t)2048*1024, 1024, 256);
  transpose_bf16<<<dim3(256/64, 1024/64), 256, 0, stream>>>(e_wv, t_wqkv_e + (size_t)2304*1024, 1024, 256);
  transpose_bf16<<<dim3(1024/64, 2048/64), 256, 0, stream>>>(e_wo, t_wo_e, 2048, 1024);
  transpose_bf16<<<dim3(4096/64, 1024/64), 256, 0, stream>>>(e_wgate, t_wgate_e, 1024, 4096);
  transpose_bf16<<<dim3(4096/64, 1024/64), 256, 0, stream>>>(e_wup, t_wup_e, 1024, 4096);
  transpose_bf16<<<dim3(1024/64, 4096/64), 256, 0, stream>>>(e_wdown, t_wdown_e, 4096, 1024);

  // 2) adaRMS modulation
  mod_kernel<<<96, 256, 0, stream>>>(cond, e_ada1_w, e_ada1_b, e_ada2_w, e_ada2_b, mod1, mod2);

  // 3) pre-attention RMSNorms
  rms_kernel<<<3072, 256, 0, stream>>>(x_prefix, h_p, 2048, p_ln1, nullptr, 0, 0);
  rms_kernel<<<256, 256, 0, stream>>>(x_expert, h_e, 1024, mod1, mod1 + 1024, 64, 3072);

  // 4) QKV projections
  gemm_bt<0><<<dim3(20, 24), 256, 0, stream>>>(h_p, 2048, BIG, 0, 0, t_wqkv_p, 2048,
                                               qkv_p, 2560, 2048, nullptr, nullptr, 0, 1, 0);
  gemm_bt<0><<<dim3(20, 2), 256, 0, stream>>>(h_e, 1024, BIG, 0, 0, t_wqkv_e, 1024,
                                              qkv_e, 2560, 1024, nullptr, nullptr, 0, 1, 0);

  // 5) RoPE + layout
  rope_kernel<<<3328, 256, 0, stream>>>(qkv_p, qkv_e, pos, q_all, k_all, vTb);

  // 6) flash attention
  attn_kernel<<<dim3(13, 8, 4), 256, 0, stream>>>(q_all, k_all, vTb, mask, att);

  // 7) output projections + residuals
  gemm_bt<2><<<dim3(16, 24), 256, 0, stream>>>(att, 2048, 768, 832, 0, t_wo_p, 2048,
                                               res_p, 2048, 2048, x_prefix, nullptr, 0, 1, 0);
  gemm_bt<4><<<dim3(8, 2, 4), 256, 0, stream>>>(att, 2048, 64, 832, 768, t_wo_e, 2048,
                                                pwo, 1024, 512, nullptr, nullptr, 0, 1, PSTRIDE_E);
  reduce_gated<<<256, 256, 0, stream>>>(pwo, PSTRIDE_E, 4, x_expert, mod1 + 2048, 3072, 64, 1024,
                                        res_e, (256 * 1024) / 4);

  // 8) pre-MLP RMSNorms
  rms_kernel<<<3072, 256, 0, stream>>>(res_p, h2_p, 2048, p_ln2, nullptr, 0, 0);
  rms_kernel<<<256, 256, 0, stream>>>(res_e, h2_e, 1024, mod2, mod2 + 1024, 64, 3072);

  // 9) prefix MLP: gate/up via gemm_bt (128², 3072 blocks, n-strip —
  //    measured 308 µs each in round 3 vs gemm8's 319); down split-K4 gemm8.
  gemm_bt<0><<<dim3(128, 24), 256, 0, stream>>>(h2_p, 2048, BIG, 0, 0, t_wgate_p, 2048,
                                                g_p, 16384, 2048, nullptr, nullptr, 0, 1, 0);
  gemm_bt<1><<<dim3(128, 24), 256, 0, stream>>>(h2_p, 2048, BIG, 0, 0, t_wup_p, 2048,
                                                g_p, 16384, 2048, g_p, nullptr, 0, 1, 0);
  gemm8<4><<<dim3(8, 12, 4), 512, 0, stream>>>(g_p, 16384, t_wdown_p, 16384,
                                               partials, 2048, 4096, nullptr, PSTRIDE_P);
  reduce4<<<2048, 256, 0, stream>>>(partials, res_p, (float*)d_out,
                                    (3072 * 2048) / 4, PSTRIDE_P);

  // 10) expert MLP: merged gate+up split-K4, fused gelu, down split-K8
  gemm_bt<4><<<dim3(64, 2, 4), 256, 0, stream>>>(h2_e, 1024, BIG, 0, 0, t_wgate_e, 1024,
                                                 pgu, 8192, 256, nullptr, nullptr, 0, 1, PSTRIDE_GU);
  fuse_gelu<<<1024, 256, 0, stream>>>(pgu, g_e, (256 * 4096) / 4, PSTRIDE_GU);
  gemm_bt<4><<<dim3(8, 2, 8), 256, 0, stream>>>(g_e, 4096, BIG, 0, 0, t_wdown_e, 4096,
                                                pd, 1024, 512, nullptr, nullptr, 0, 1, PSTRIDE_E);
  reduce_gated<<<256, 256, 0, stream>>>(pd, PSTRIDE_E, 8, res_e, mod2 + 2048, 3072, 64, 1024,
                                        (float*)d_out + (size_t)3072 * 2048, (256 * 1024) / 4);
}

// Round 13
// 1254.454 us; speedup vs baseline: 1.0436x; 1.0436x over previous
//
#include <hip/hip_runtime.h>
#include <stdint.h>

typedef unsigned short ushort_t;
typedef __attribute__((ext_vector_type(8))) short short8;
typedef __attribute__((ext_vector_type(4))) float f32x4;

#define DEVINL __device__ __forceinline__

DEVINL ushort_t f2bf(float f){
  union { float f; uint32_t u; } v; v.f = f;
  uint32_t u = v.u;
  uint32_t r = (u + 0x7fffu + ((u >> 16) & 1u)) >> 16;
  return (ushort_t)r;
}
DEVINL float bf2f(ushort_t h){
  union { uint32_t u; float f; } v; v.u = ((uint32_t)h) << 16;
  return v.f;
}
DEVINL f32x4 mfma16(short8 a, short8 b, f32x4 c){
  return __builtin_amdgcn_mfma_f32_16x16x32_bf16(a, b, c, 0, 0, 0);
}
DEVINL void gload_lds16(const void* g, void* l){
  __builtin_amdgcn_global_load_lds((const __attribute__((address_space(1))) void*)g,
                                   (__attribute__((address_space(3))) void*)l, 16, 0, 0);
}
DEVINL float gelu_tanh(float x){
  return 0.5f * x * (1.f + tanhf(0.7978845608028654f * (x + 0.044715f * x * x * x)));
}

#define BAR() __builtin_amdgcn_s_barrier()
#define LGK0() asm volatile("s_waitcnt lgkmcnt(0)" ::: "memory")
#define VMC4() asm volatile("s_waitcnt vmcnt(4)" ::: "memory")
#define VMC0() asm volatile("s_waitcnt vmcnt(0)" ::: "memory")
#define PRIO1() __builtin_amdgcn_s_setprio(1)
#define PRIO0() __builtin_amdgcn_s_setprio(0)

// ---------------------------------------------------------------------------
// Transpose + fp32->bf16: W[K][N] -> Wt[N][K]
// ---------------------------------------------------------------------------
__global__ void transpose_bf16(const float* __restrict__ W, ushort_t* __restrict__ Wt,
                               int K, int N)
{
  __shared__ ushort_t tile[64 * 65];
  const int t = threadIdx.x;
  const int k0 = blockIdx.y * 64, n0 = blockIdx.x * 64;
#pragma unroll
  for (int rr = 0; rr < 4; ++rr){
    const int row = rr * 16 + (t >> 4);
    const int c4 = (t & 15) * 4;
    float4 v = *(const float4*)&W[(size_t)(k0 + row) * N + n0 + c4];
    ushort_t* dst = &tile[row * 65 + c4];
    dst[0] = f2bf(v.x); dst[1] = f2bf(v.y); dst[2] = f2bf(v.z); dst[3] = f2bf(v.w);
  }
  __syncthreads();
  const int n = t >> 2, kc = (t & 3) * 16;
  __align__(16) ushort_t tmp[16];
#pragma unroll
  for (int j = 0; j < 16; ++j) tmp[j] = tile[(kc + j) * 65 + n];
  ushort_t* out = &Wt[(size_t)(n0 + n) * K + k0 + kc];
  *(short8*)&out[0] = *(short8*)&tmp[0];
  *(short8*)&out[8] = *(short8*)&tmp[8];
}

// ---------------------------------------------------------------------------
// mod1/mod2 = adarms_cond @ e_adaX_w + e_adaX_b   (tiny GEMV)
// ---------------------------------------------------------------------------
__global__ void mod_kernel(const float* __restrict__ cond,
                           const float* __restrict__ w1, const float* __restrict__ b1,
                           const float* __restrict__ w2, const float* __restrict__ b2,
                           float* __restrict__ mod1, float* __restrict__ mod2)
{
  __shared__ float cs[1024];
  const int bid = blockIdx.x, tid = threadIdx.x;
  const int which = bid / 48, rem = bid % 48, b = rem / 12, j0 = (rem % 12) * 256;
  const float* W = which ? w2 : w1;
  const float* bias = which ? b2 : b1;
  float* out = which ? mod2 : mod1;
#pragma unroll
  for (int i = 0; i < 4; ++i) cs[i * 256 + tid] = cond[b * 1024 + i * 256 + tid];
  __syncthreads();
  const int j = j0 + tid;
  float acc = bias[j];
  for (int k = 0; k < 1024; ++k) acc = fmaf(cs[k], W[(size_t)k * 3072 + j], acc);
  out[b * 3072 + j] = acc;
}

// ---------------------------------------------------------------------------
// RMSNorm -> bf16
// ---------------------------------------------------------------------------
__global__ void rms_kernel(const float* __restrict__ x, ushort_t* __restrict__ out, int D,
                           const float* __restrict__ sw, const float* __restrict__ sh,
                           int mod_rpb, int mod_stride)
{
  const int row = blockIdx.x, tid = threadIdx.x;
  const float* xr = x + (size_t)row * D;
  const int nc = D >> 10;
  float ss = 0.f;
  for (int c = 0; c < nc; ++c){
    float4 v = *(const float4*)&xr[c * 1024 + tid * 4];
    ss += v.x * v.x + v.y * v.y + v.z * v.z + v.w * v.w;
  }
  for (int o = 32; o > 0; o >>= 1) ss += __shfl_xor(ss, o);
  __shared__ float red[4];
  if ((tid & 63) == 0) red[tid >> 6] = ss;
  __syncthreads();
  const float scale = rsqrtf((red[0] + red[1] + red[2] + red[3]) / (float)D + 1e-6f);
  const float* swp = sw;
  const float* shp = sh;
  if (mod_rpb){
    int bb = row / mod_rpb;
    swp += (size_t)bb * mod_stride;
    if (shp) shp += (size_t)bb * mod_stride;
  }
  for (int c = 0; c < nc; ++c){
    const int d = c * 1024 + tid * 4;
    float4 v = *(const float4*)&xr[d];
    float vv[4] = {v.x, v.y, v.z, v.w};
#pragma unroll
    for (int i = 0; i < 4; ++i){
      float tv = vv[i] * scale * (1.f + swp[d + i]);
      if (shp) tv += shp[d + i];
      out[(size_t)row * D + d + i] = f2bf(tv);
    }
  }
}

// ---------------------------------------------------------------------------
// RoPE + layout.  K and V stored with 16B-chunk XOR permutation inside each
// 64-token tile (conflict-free attn LDS reads; both-sides rule).
// ---------------------------------------------------------------------------
__global__ void rope_kernel(const ushort_t* __restrict__ qkv_p, const ushort_t* __restrict__ qkv_e,
                            const int* __restrict__ pos_ids,
                            ushort_t* __restrict__ q_all, ushort_t* __restrict__ k_all,
                            ushort_t* __restrict__ vT)
{
  const int tok = blockIdx.x, tid = threadIdx.x;
  int b, s;
  const ushort_t* src;
  if (tok < 3072){ b = tok / 768; s = tok - b * 768; src = qkv_p + (size_t)tok * 2560; }
  else { int te = tok - 3072; b = te >> 6; s = 768 + (te & 63); src = qkv_e + (size_t)te * 2560; }
  const int pos = pos_ids[b * 832 + s];
  __shared__ float cs[128], sn[128];
  if (tid < 128){
    float f = powf(10000.f, -(float)tid * (1.f / 128.f));
    float a = (float)pos * f;
    cs[tid] = cosf(a); sn[tid] = sinf(a);
  }
  __syncthreads();
#pragma unroll
  for (int c = 0; c < 10; ++c){
    const int n = c * 256 + tid;
    const float v = bf2f(src[n]);
    if (n < 2048){
      const int h = n >> 8, d = n & 255;
      const float o = bf2f(src[(h << 8) + ((d < 128) ? (d + 128) : (d - 128))]);
      const int dd = d & 127;
      const float r = (d < 128) ? v * cs[dd] - o * sn[dd] : v * cs[dd] + o * sn[dd];
      q_all[(((size_t)(b * 8 + h)) * 832 + s) * 256 + d] = f2bf(r);
    } else if (n < 2304){
      const int d = n - 2048;
      const float o = bf2f(src[2048 + ((d < 128) ? (d + 128) : (d - 128))]);
      const int dd = d & 127;
      const float r = (d < 128) ? v * cs[dd] - o * sn[dd] : v * cs[dd] + o * sn[dd];
      const int ck = d >> 3, e = d & 7;
      const int ck2 = ck ^ (s & 7);
      k_all[((size_t)(b * 832) + s) * 256 + (ck2 << 3) + e] = f2bf(r);
    } else {
      const int d = n - 2304;
      const int stile = s >> 6, sl = s & 63;
      const int cv = sl >> 3, e = sl & 7;
      const int cv2 = cv ^ (d & 7);
      vT[((size_t)(b * 256) + d) * 832 + (stile << 6) + (cv2 << 3) + e] = src[n];
    }
  }
}

// ---------------------------------------------------------------------------
// Flash attention (K/V chunk-deswizzle on ds_read)
// ---------------------------------------------------------------------------
__global__ void __launch_bounds__(256, 2)
attn_kernel(const ushort_t* __restrict__ q_all, const ushort_t* __restrict__ k_all,
            const ushort_t* __restrict__ vT, const float* __restrict__ mask,
            ushort_t* __restrict__ att)
{
  __shared__ __align__(16) ushort_t Ks[64 * 256];
  __shared__ __align__(16) ushort_t Vs[256 * 64];
  __shared__ __align__(16) ushort_t Ps[4][16 * 72];
  const int tid = threadIdx.x, lane = tid & 63, wid = tid >> 6;
  const int l15 = lane & 15, lg = lane >> 4;
  const int qt = blockIdx.x, h = blockIdx.y, b = blockIdx.z;
  const int q0 = qt * 64 + wid * 16;
  const int x7 = l15 & 7;

  short8 qf[8];
  {
    const ushort_t* qr = q_all + (((size_t)(b * 8 + h) * 832) + q0 + l15) * 256;
#pragma unroll
    for (int s = 0; s < 8; ++s) qf[s] = *(const short8*)&qr[s * 32 + lg * 8];
  }

  f32x4 accO[16] = {};
  float mrow[4] = {-3.0e38f, -3.0e38f, -3.0e38f, -3.0e38f};
  float lrow[4] = {0.f, 0.f, 0.f, 0.f};

  for (int kt = 0; kt < 13; ++kt){
    const int s0 = kt * 64;
#pragma unroll
    for (int i = 0; i < 8; ++i){
      const int o = i * 256 + tid;
      gload_lds16(k_all + ((size_t)(b * 832) + s0 + (o >> 5)) * 256 + (o & 31) * 8, &Ks[o * 8]);
      gload_lds16(vT + ((size_t)(b * 256) + (o >> 3)) * 832 + s0 + (o & 7) * 8, &Vs[o * 8]);
    }
    __syncthreads();

    f32x4 sc[4] = {};
#pragma unroll
    for (int s = 0; s < 8; ++s){
#pragma unroll
      for (int nf = 0; nf < 4; ++nf){
        short8 kb = *(const short8*)&Ks[(nf * 16 + l15) * 256 + (((s * 4 + lg) ^ x7) << 3)];
        sc[nf] = mfma16(qf[s], kb, sc[nf]);
      }
    }
#pragma unroll
    for (int nf = 0; nf < 4; ++nf){
#pragma unroll
      for (int r = 0; r < 4; ++r){
        const int q = q0 + lg * 4 + r;
        const int kk = s0 + nf * 16 + l15;
        sc[nf][r] = sc[nf][r] * 0.0625f + mask[((size_t)b * 832 + q) * 832 + kk];
      }
    }
    float al[4];
#pragma unroll
    for (int r = 0; r < 4; ++r){
      float tm = fmaxf(fmaxf(sc[0][r], sc[1][r]), fmaxf(sc[2][r], sc[3][r]));
      tm = fmaxf(tm, __shfl_xor(tm, 1));
      tm = fmaxf(tm, __shfl_xor(tm, 2));
      tm = fmaxf(tm, __shfl_xor(tm, 4));
      tm = fmaxf(tm, __shfl_xor(tm, 8));
      const float mnew = fmaxf(mrow[r], tm);
      al[r] = __expf(mrow[r] - mnew);
      mrow[r] = mnew;
      float rs = 0.f;
#pragma unroll
      for (int nf = 0; nf < 4; ++nf){
        const float p = __expf(sc[nf][r] - mnew);
        rs += p;
        Ps[wid][(lg * 4 + r) * 72 + nf * 16 + l15] = f2bf(p);
      }
      rs += __shfl_xor(rs, 1);
      rs += __shfl_xor(rs, 2);
      rs += __shfl_xor(rs, 4);
      rs += __shfl_xor(rs, 8);
      lrow[r] = lrow[r] * al[r] + rs;
    }
#pragma unroll
    for (int nd = 0; nd < 16; ++nd){
#pragma unroll
      for (int r = 0; r < 4; ++r) accO[nd][r] *= al[r];
    }
#pragma unroll
    for (int ks = 0; ks < 2; ++ks){
      short8 pa = *(const short8*)&Ps[wid][l15 * 72 + ks * 32 + lg * 8];
#pragma unroll
      for (int nd = 0; nd < 16; ++nd){
        short8 vb = *(const short8*)&Vs[(nd * 16 + l15) * 64 + (((ks * 4 + lg) ^ x7) << 3)];
        accO[nd] = mfma16(pa, vb, accO[nd]);
      }
    }
    __syncthreads();
  }
#pragma unroll
  for (int nd = 0; nd < 16; ++nd){
#pragma unroll
    for (int r = 0; r < 4; ++r){
      const int q = q0 + lg * 4 + r;
      const int d = nd * 16 + l15;
      att[((size_t)(b * 832) + q) * 2048 + h * 256 + d] = f2bf(accO[nd][r] / lrow[r]);
    }
  }
}

// ---------------------------------------------------------------------------
// 128x128 2-phase GEMM (proven) + n-strip bijective XCD decode
// ---------------------------------------------------------------------------
template<int EPI>
__global__ void __launch_bounds__(256, 2)
gemm_bt(const ushort_t* __restrict__ A, int lda, int a_rpb, int a_bstride, int a_r0,
        const ushort_t* __restrict__ Bt, int ldb,
        void* __restrict__ Cv, int N, int K,
        const void* __restrict__ Xv,
        const float* __restrict__ gatep, int gate_stride, int gate_rpb,
        size_t pstride)
{
  __shared__ __align__(16) ushort_t As[128 * 64];
  __shared__ __align__(16) ushort_t Bs[128 * 64];
  const int tid = threadIdx.x;
  const int lane = tid & 63;
  const int l15 = lane & 15, lg = lane >> 4;
  const int wid = tid >> 6;
  const int wm = (wid >> 1) * 64, wn = (wid & 1) * 64;
  const int gx = gridDim.x, gy = gridDim.y, nwg = gx * gy;
  const int orig = blockIdx.y * gx + blockIdx.x;
  const int q = nwg >> 3, r = nwg & 7;
  const int xcd = orig & 7, lo = orig >> 3;
  const int wg = (xcd < r ? xcd * (q + 1) : r * (q + 1) + (xcd - r) * q) + lo;
  const int m0 = (wg % gy) * 128, n0 = (wg / gy) * 128;
  const int z = blockIdx.z;
  const int kbeg = z * K, kend = z * K + K;

  size_t abase[4], bbase[4];
  const int k8 = (tid & 7) * 8;
#pragma unroll
  for (int i = 0; i < 4; ++i){
    const int row = (i * 256 + tid) >> 3;
    const int rr = m0 + row;
    const int bb = rr / a_rpb;
    const int arow = bb * a_bstride + a_r0 + (rr - bb * a_rpb);
    abase[i] = (size_t)arow * lda + k8;
    bbase[i] = (size_t)(n0 + row) * ldb + k8;
  }

  f32x4 acc[4][4] = {};

  for (int kt = kbeg; kt < kend; kt += 64){
#pragma unroll
    for (int i = 0; i < 4; ++i){
      gload_lds16(A + abase[i] + kt, &As[(i * 256 + tid) * 8]);
      gload_lds16(Bt + bbase[i] + kt, &Bs[(i * 256 + tid) * 8]);
    }
    __syncthreads();
#pragma unroll
    for (int s = 0; s < 2; ++s){
      const int ko = s * 32 + lg * 8;
      short8 af[4], bfr[4];
#pragma unroll
      for (int i = 0; i < 4; ++i) af[i] = *(const short8*)&As[(wm + i * 16 + l15) * 64 + ko];
#pragma unroll
      for (int j = 0; j < 4; ++j) bfr[j] = *(const short8*)&Bs[(wn + j * 16 + l15) * 64 + ko];
#pragma unroll
      for (int i = 0; i < 4; ++i)
#pragma unroll
        for (int j = 0; j < 4; ++j)
          acc[i][j] = mfma16(af[i], bfr[j], acc[i][j]);
    }
    __syncthreads();
  }

#pragma unroll
  for (int i = 0; i < 4; ++i){
#pragma unroll
    for (int rr = 0; rr < 4; ++rr){
      const int m = m0 + wm + i * 16 + lg * 4 + rr;
#pragma unroll
      for (int j = 0; j < 4; ++j){
        const int n = n0 + wn + j * 16 + l15;
        const size_t idx = (size_t)m * N + n;
        const float v = acc[i][j][rr];
        if (EPI == 0){
          ((ushort_t*)Cv)[idx] = f2bf(v);
        } else if (EPI == 1){
          const float g = bf2f(((const ushort_t*)Xv)[idx]);
          ((ushort_t*)Cv)[idx] = f2bf(gelu_tanh(g) * v);
        } else if (EPI == 2){
          ((float*)Cv)[idx] = ((const float*)Xv)[idx] + v;
        } else if (EPI == 3){
          const int bb = m / gate_rpb;
          ((float*)Cv)[idx] = ((const float*)Xv)[idx] + gatep[(size_t)bb * gate_stride + n] * v;
        } else {
          ((float*)Cv)[(size_t)z * pstride + idx] = v;
        }
      }
    }
  }
}

// ---------------------------------------------------------------------------
// 256x256 GEMM, 2 phases per K-tile, hoisted addresses, n-strip XCD mapping
// ---------------------------------------------------------------------------
#define MMAQ(AF, BF, MQ, NQ) \
  { _Pragma("unroll") for (int i_ = 0; i_ < 4; ++i_){ \
      _Pragma("unroll") for (int j_ = 0; j_ < 2; ++j_){ \
        _Pragma("unroll") for (int s_ = 0; s_ < 2; ++s_){ \
          acc[(MQ)*4 + i_][(NQ)*2 + j_] = \
            mfma16(AF[i_][s_], BF[j_][s_], acc[(MQ)*4 + i_][(NQ)*2 + j_]); } } } }

#define READA(F, BUF, OA) \
  { _Pragma("unroll") for (int i_ = 0; i_ < 4; ++i_){ \
      _Pragma("unroll") for (int s_ = 0; s_ < 2; ++s_){ \
        F[i_][s_] = *(const short8*)&(BUF)[OA[i_][s_]]; } } }

#define READB(F, BUF, OB) \
  { _Pragma("unroll") for (int j_ = 0; j_ < 2; ++j_){ \
      _Pragma("unroll") for (int s_ = 0; s_ < 2; ++s_){ \
        F[j_][s_] = *(const short8*)&(BUF)[OB[j_][s_]]; } } }

template<int EPI>
__global__ void __launch_bounds__(512, 1)
gemm8(const ushort_t* __restrict__ A, int lda,
      const ushort_t* __restrict__ Bt, int ldb,
      void* __restrict__ Cv, int N, int klen,
      const void* __restrict__ Xv, size_t pstride)
{
  __shared__ __align__(16) ushort_t As[2][256 * 64];
  __shared__ __align__(16) ushort_t Bs[2][256 * 64];

  const int tid = threadIdx.x;
  const int lane = tid & 63, wid = tid >> 6;
  const int l15 = lane & 15, lg = lane >> 4;
  const int wm = (wid >> 2) * 128, wn = (wid & 3) * 64;

  const int gx = gridDim.x, gy = gridDim.y, nwg = gx * gy;
  const int orig = blockIdx.y * gx + blockIdx.x;
  const int q = nwg >> 3, r = nwg & 7;
  const int xcd = orig & 7, lo = orig >> 3;
  const int wg = (xcd < r ? xcd * (q + 1) : r * (q + 1) + (xcd - r) * q) + lo;
  const int m0 = (wg % gy) * 256, n0 = (wg / gy) * 256;
  const int z = blockIdx.z;
  const size_t k0 = (size_t)z * klen;
  const int NT = klen >> 6;

  uint32_t offA0[4][2], offA1[4][2], offB0[2][2], offB1[2][2];
#pragma unroll
  for (int i = 0; i < 4; ++i){
#pragma unroll
    for (int s = 0; s < 2; ++s){
      int r0 = wm + 0 * 64 + i * 16 + l15;
      int r1 = wm + 1 * 64 + i * 16 + l15;
      offA0[i][s] = r0 * 64 + (((s * 4 + lg) ^ (r0 & 7)) << 3);
      offA1[i][s] = r1 * 64 + (((s * 4 + lg) ^ (r1 & 7)) << 3);
    }
  }
#pragma unroll
  for (int j = 0; j < 2; ++j){
#pragma unroll
    for (int s = 0; s < 2; ++s){
      int r0 = wn + 0 * 32 + j * 16 + l15;
      int r1 = wn + 1 * 32 + j * 16 + l15;
      offB0[j][s] = r0 * 64 + (((s * 4 + lg) ^ (r0 & 7)) << 3);
      offB1[j][s] = r1 * 64 + (((s * 4 + lg) ^ (r1 & 7)) << 3);
    }
  }

  const ushort_t* gptr[4][2];
  uint32_t ldso[2];
#pragma unroll
  for (int c = 0; c < 2; ++c){
    const int idx = c * 512 + tid;
    const int row = idx >> 3, slot = idx & 7;
    const uint32_t sw = (uint32_t)((slot ^ (row & 7)) << 3);
    ldso[c] = (uint32_t)idx * 8;
    gptr[0][c] = A  + (size_t)(m0 + row) * lda + k0 + sw;
    gptr[1][c] = A  + (size_t)(m0 + 128 + row) * lda + k0 + sw;
    gptr[2][c] = Bt + (size_t)(n0 + row) * ldb + k0 + sw;
    gptr[3][c] = Bt + (size_t)(n0 + 128 + row) * ldb + k0 + sw;
  }

  auto stage = [&](int buf, int half, int kt){
    ushort_t* base = (half < 2) ? &As[buf][(half & 1) * 8192] : &Bs[buf][(half & 1) * 8192];
#pragma unroll
    for (int c = 0; c < 2; ++c)
      gload_lds16(gptr[half][c] + kt, base + ldso[c]);
  };

  stage(0, 0, 0); stage(0, 1, 0); stage(0, 2, 0); stage(0, 3, 0);
  if (NT > 1){ stage(1, 2, 64); stage(1, 3, 64); VMC4(); } else { VMC0(); }
  BAR();

  short8 af[4][2], bq0[2][2], bq1[2][2];
  f32x4 acc[8][4] = {};

  for (int t = 0; t < NT; ++t){
    const int cur = t & 1, nxt = cur ^ 1;
    const int kc1 = (t + 1) << 6, kc2 = (t + 2) << 6;
    const ushort_t* Ac = As[cur];
    const ushort_t* Bc = Bs[cur];
    READA(af, Ac, offA0);
    READB(bq0, Bc, offB0);
    READB(bq1, Bc, offB1);
    if (t + 1 < NT){ stage(nxt, 0, kc1); stage(nxt, 1, kc1); }
    BAR(); LGK0();
    PRIO1(); MMAQ(af, bq0, 0, 0); MMAQ(af, bq1, 0, 1); PRIO0(); BAR();
    READA(af, Ac, offA1);
    if (t + 2 < NT){ stage(cur, 2, kc2); stage(cur, 3, kc2); VMC4(); } else { VMC0(); }
    BAR(); LGK0();
    PRIO1(); MMAQ(af, bq1, 1, 1); MMAQ(af, bq0, 1, 0); PRIO0(); BAR();
  }

#pragma unroll
  for (int i = 0; i < 8; ++i){
#pragma unroll
    for (int rr = 0; rr < 4; ++rr){
      const int m = m0 + wm + i * 16 + lg * 4 + rr;
#pragma unroll
      for (int j = 0; j < 4; ++j){
        const int n = n0 + wn + j * 16 + l15;
        const size_t idx = (size_t)m * N + n;
        const float v = acc[i][j][rr];
        if (EPI == 0){
          ((ushort_t*)Cv)[idx] = f2bf(v);
        } else if (EPI == 1){
          const float g = bf2f(((const ushort_t*)Xv)[idx]);
          ((ushort_t*)Cv)[idx] = f2bf(gelu_tanh(g) * v);
        } else {
          ((float*)Cv)[(size_t)z * pstride + idx] = v;
        }
      }
    }
  }
}

// out = res + sum_{z<4} part[z]   (prefix down reduce)
__global__ void reduce4(const float* __restrict__ part, const float* __restrict__ res,
                        float* __restrict__ out, int total4, size_t pstride)
{
  int i = blockIdx.x * blockDim.x + threadIdx.x;
  const int stride = gridDim.x * blockDim.x;
  for (; i < total4; i += stride){
    const size_t e = (size_t)i * 4;
    float4 a = *(const float4*)&res[e];
#pragma unroll
    for (int z = 0; z < 4; ++z){
      float4 p = *(const float4*)&part[(size_t)z * pstride + e];
      a.x += p.x; a.y += p.y; a.z += p.z; a.w += p.w;
    }
    *(float4*)&out[e] = a;
  }
}

// g_out[row][n] = bf16( gelu(sum_z P[z][row][n]) * sum_z P[z][row][4096+n] )
// P rows 8192 wide (gate|up halves); nz=4.
__global__ void fuse_gelu(const float* __restrict__ P, ushort_t* __restrict__ out,
                          int total4, size_t zstride)
{
  int i = blockIdx.x * blockDim.x + threadIdx.x;
  const int stride = gridDim.x * blockDim.x;
  for (; i < total4; i += stride){
    const size_t e = (size_t)i * 4;
    const int row = (int)(e >> 12);
    const int n   = (int)(e & 4095);
    const size_t gb = (size_t)row * 8192 + n;
    float4 g = *(const float4*)&P[gb];
    float4 u = *(const float4*)&P[gb + 4096];
#pragma unroll
    for (int z = 1; z < 4; ++z){
      float4 a = *(const float4*)&P[(size_t)z * zstride + gb];
      float4 b = *(const float4*)&P[(size_t)z * zstride + gb + 4096];
      g.x += a.x; g.y += a.y; g.z += a.z; g.w += a.w;
      u.x += b.x; u.y += b.y; u.z += b.z; u.w += b.w;
    }
    out[e + 0] = f2bf(gelu_tanh(g.x) * u.x);
    out[e + 1] = f2bf(gelu_tanh(g.y) * u.y);
    out[e + 2] = f2bf(gelu_tanh(g.z) * u.z);
    out[e + 3] = f2bf(gelu_tanh(g.w) * u.w);
  }
}

// out = base + gate[b][n] * sum_{z<nz} part[z]
__global__ void reduce_gated(const float* __restrict__ part, size_t pstride, int nz,
                             const float* __restrict__ base, const float* __restrict__ gate,
                             int gstride, int rpb, int N,
                             float* __restrict__ out, int total4)
{
  int i = blockIdx.x * blockDim.x + threadIdx.x;
  const int stride = gridDim.x * blockDim.x;
  for (; i < total4; i += stride){
    const size_t e = (size_t)i * 4;
    const int row = (int)(e / N), n = (int)(e % N);
    const int b = row / rpb;
    float4 s = *(const float4*)&part[e];
    for (int z = 1; z < nz; ++z){
      float4 p = *(const float4*)&part[(size_t)z * pstride + e];
      s.x += p.x; s.y += p.y; s.z += p.z; s.w += p.w;
    }
    float4 bs = *(const float4*)&base[e];
    const float* gp = &gate[(size_t)b * gstride + n];
    bs.x += gp[0] * s.x; bs.y += gp[1] * s.y; bs.z += gp[2] * s.z; bs.w += gp[3] * s.w;
    *(float4*)&out[e] = bs;
  }
}

// ---------------------------------------------------------------------------
extern "C" void kernel_launch(void* const* d_in, const int* in_sizes, int n_in,
                              void* d_out, int out_size, void* d_ws, size_t ws_size,
                              hipStream_t stream)
{
  const float* x_prefix = (const float*)d_in[0];
  const float* x_expert = (const float*)d_in[1];
  const float* mask     = (const float*)d_in[2];
  const float* cond     = (const float*)d_in[3];
  const int*   pos      = (const int*)d_in[4];
  const float* p_ln1    = (const float*)d_in[5];
  const float* p_wq     = (const float*)d_in[6];
  const float* p_wk     = (const float*)d_in[7];
  const float* p_wv     = (const float*)d_in[8];
  const float* p_wo     = (const float*)d_in[9];
  const float* p_ln2    = (const float*)d_in[10];
  const float* p_wgate  = (const float*)d_in[11];
  const float* p_wup    = (const float*)d_in[12];
  const float* p_wdown  = (const float*)d_in[13];
  const float* e_ada1_w = (const float*)d_in[14];
  const float* e_ada1_b = (const float*)d_in[15];
  const float* e_wq     = (const float*)d_in[16];
  const float* e_wk     = (const float*)d_in[17];
  const float* e_wv     = (const float*)d_in[18];
  const float* e_wo     = (const float*)d_in[19];
  const float* e_ada2_w = (const float*)d_in[20];
  const float* e_ada2_b = (const float*)d_in[21];
  const float* e_wgate  = (const float*)d_in[22];
  const float* e_wup    = (const float*)d_in[23];
  const float* e_wdown  = (const float*)d_in[24];

  char* ws = (char*)d_ws;
  size_t off = 0;
  auto alloc = [&](size_t bytes) -> char* {
    char* p = ws + off;
    off += bytes;
    off = (off + 255) & ~(size_t)255;
    return p;
  };

  ushort_t* t_wqkv_p  = (ushort_t*)alloc((size_t)2560 * 2048 * 2);
  ushort_t* t_wo_p    = (ushort_t*)alloc((size_t)2048 * 2048 * 2);
  ushort_t* t_wgate_p = (ushort_t*)alloc((size_t)16384 * 2048 * 2);
  ushort_t* t_wup_p   = (ushort_t*)alloc((size_t)16384 * 2048 * 2);
  ushort_t* t_wdown_p = (ushort_t*)alloc((size_t)2048 * 16384 * 2);
  ushort_t* t_wqkv_e  = (ushort_t*)alloc((size_t)2560 * 1024 * 2);
  ushort_t* t_wo_e    = (ushort_t*)alloc((size_t)1024 * 2048 * 2);
  ushort_t* t_wgate_e = (ushort_t*)alloc((size_t)4096 * 1024 * 2);  // contiguous with wup_e
  ushort_t* t_wup_e   = (ushort_t*)alloc((size_t)4096 * 1024 * 2);
  ushort_t* t_wdown_e = (ushort_t*)alloc((size_t)1024 * 4096 * 2);
  float* mod1 = (float*)alloc((size_t)4 * 3072 * 4);
  float* mod2 = (float*)alloc((size_t)4 * 3072 * 4);
  float* res_p = (float*)alloc((size_t)3072 * 2048 * 4);
  float* res_e = (float*)alloc((size_t)256 * 1024 * 4);
  ushort_t* h2_p = (ushort_t*)alloc((size_t)3072 * 2048 * 2);
  ushort_t* h2_e = (ushort_t*)alloc((size_t)256 * 1024 * 2);
  ushort_t* g_e  = (ushort_t*)alloc((size_t)256 * 4096 * 2);

  const size_t zone_off = off;
  ushort_t* h_p   = (ushort_t*)alloc((size_t)3072 * 2048 * 2);
  ushort_t* h_e   = (ushort_t*)alloc((size_t)256 * 1024 * 2);
  ushort_t* qkv_p = (ushort_t*)alloc((size_t)3072 * 2560 * 2);
  ushort_t* qkv_e = (ushort_t*)alloc((size_t)256 * 2560 * 2);
  ushort_t* q_all = (ushort_t*)alloc((size_t)4 * 8 * 832 * 256 * 2);
  ushort_t* k_all = (ushort_t*)alloc((size_t)4 * 832 * 256 * 2);
  ushort_t* vTb   = (ushort_t*)alloc((size_t)4 * 256 * 832 * 2);
  ushort_t* att   = (ushort_t*)alloc((size_t)4 * 832 * 2048 * 2);
  const size_t phase1_end = off;
  ushort_t* g_p = (ushort_t*)(ws + zone_off); // [3072][16384] bf16, MLP phase only

  // overlays (stream-ordered):
  float* partials = (float*)t_wgate_p;           // prefix down partials [4][3072][2048]
  const size_t PSTRIDE_P = (size_t)3072 * 2048;
  float* pwo = (float*)(ws + zone_off);          // e-wo partials over h_p
  const size_t PSTRIDE_E = (size_t)256 * 1024;
  float* pgu = (float*)t_wgate_p;                // expert merged gate|up partials [4][256][8192]
  const size_t PSTRIDE_GU = (size_t)256 * 8192;
  float* pd = pgu + (size_t)4 * PSTRIDE_GU;      // expert down partials [8][256][1024]

  const size_t g_p_end = zone_off + (size_t)3072 * 16384 * 2;
  const size_t needed = (phase1_end > g_p_end) ? phase1_end : g_p_end;
  if (ws_size < needed) return;

  const int BIG = 1 << 30;

  // 1) weight transposes
  transpose_bf16<<<dim3(2048/64, 2048/64), 256, 0, stream>>>(p_wq, t_wqkv_p, 2048, 2048);
  transpose_bf16<<<dim3(256/64, 2048/64), 256, 0, stream>>>(p_wk, t_wqkv_p + (size_t)2048*2048, 2048, 256);
  transpose_bf16<<<dim3(256/64, 2048/64), 256, 0, stream>>>(p_wv, t_wqkv_p + (size_t)2304*2048, 2048, 256);
  transpose_bf16<<<dim3(2048/64, 2048/64), 256, 0, stream>>>(p_wo, t_wo_p, 2048, 2048);
  transpose_bf16<<<dim3(16384/64, 2048/64), 256, 0, stream>>>(p_wgate, t_wgate_p, 2048, 16384);
  transpose_bf16<<<dim3(16384/64, 2048/64), 256, 0, stream>>>(p_wup, t_wup_p, 2048, 16384);
  transpose_bf16<<<dim3(2048/64, 16384/64), 256, 0, stream>>>(p_wdown, t_wdown_p, 16384, 2048);
  transpose_bf16<<<dim3(2048/64, 1024/64), 256, 0, stream>>>(e_wq, t_wqkv_e, 1024, 2048);
  transpose_bf16<<<dim3(256/64, 1024/64), 256, 0, stream>>>(e_wk, t_wqkv_e + (size_t)2048*1024, 1024, 256);
  transpose_bf16<<<dim3(256/64, 1024/64), 256, 0, stream>>>(e_wv, t_wqkv_e + (size_t)2304*1024, 1024, 256);
  transpose_bf16<<<dim3(1024/64, 2048/64), 256, 0, stream>>>(e_wo, t_wo_e, 2048, 1024);
  transpose_bf16<<<dim3(4096/64, 1024/64), 256, 0, stream>>>(e_wgate, t_wgate_e, 1024, 4096);
  transpose_bf16<<<dim3(4096/64, 1024/64), 256, 0, stream>>>(e_wup, t_wup_e, 1024, 4096);
  transpose_bf16<<<dim3(1024/64, 4096/64), 256, 0, stream>>>(e_wdown, t_wdown_e, 4096, 1024);

  // 2) adaRMS modulation
  mod_kernel<<<96, 256, 0, stream>>>(cond, e_ada1_w, e_ada1_b, e_ada2_w, e_ada2_b, mod1, mod2);

  // 3) pre-attention RMSNorms
  rms_kernel<<<3072, 256, 0, stream>>>(x_prefix, h_p, 2048, p_ln1, nullptr, 0, 0);
  rms_kernel<<<256, 256, 0, stream>>>(x_expert, h_e, 1024, mod1, mod1 + 1024, 64, 3072);

  // 4) QKV projections
  gemm_bt<0><<<dim3(20, 24), 256, 0, stream>>>(h_p, 2048, BIG, 0, 0, t_wqkv_p, 2048,
                                               qkv_p, 2560, 2048, nullptr, nullptr, 0, 1, 0);
  gemm_bt<0><<<dim3(20, 2), 256, 0, stream>>>(h_e, 1024, BIG, 0, 0, t_wqkv_e, 1024,
                                              qkv_e, 2560, 1024, nullptr, nullptr, 0, 1, 0);

  // 5) RoPE + layout
  rope_kernel<<<3328, 256, 0, stream>>>(qkv_p, qkv_e, pos, q_all, k_all, vTb);

  // 6) flash attention
  attn_kernel<<<dim3(13, 8, 4), 256, 0, stream>>>(q_all, k_all, vTb, mask, att);

  // 7) output projections + residuals
  gemm_bt<2><<<dim3(16, 24), 256, 0, stream>>>(att, 2048, 768, 832, 0, t_wo_p, 2048,
                                               res_p, 2048, 2048, x_prefix, nullptr, 0, 1, 0);
  gemm_bt<4><<<dim3(8, 2, 4), 256, 0, stream>>>(att, 2048, 64, 832, 768, t_wo_e, 2048,
                                                pwo, 1024, 512, nullptr, nullptr, 0, 1, PSTRIDE_E);
  reduce_gated<<<256, 256, 0, stream>>>(pwo, PSTRIDE_E, 4, x_expert, mod1 + 2048, 3072, 64, 1024,
                                        res_e, (256 * 1024) / 4);

  // 8) pre-MLP RMSNorms
  rms_kernel<<<3072, 256, 0, stream>>>(res_p, h2_p, 2048, p_ln2, nullptr, 0, 0);
  rms_kernel<<<256, 256, 0, stream>>>(res_e, h2_e, 1024, mod2, mod2 + 1024, 64, 3072);

  // 9) prefix MLP (round-11 best-measured): gate/up gemm8, down split-K4 + reduce4
  gemm8<0><<<dim3(64, 12, 1), 512, 0, stream>>>(h2_p, 2048, t_wgate_p, 2048,
                                                g_p, 16384, 2048, nullptr, 0);
  gemm8<1><<<dim3(64, 12, 1), 512, 0, stream>>>(h2_p, 2048, t_wup_p, 2048,
                                                g_p, 16384, 2048, g_p, 0);
  gemm8<4><<<dim3(8, 12, 4), 512, 0, stream>>>(g_p, 16384, t_wdown_p, 16384,
                                               partials, 2048, 4096, nullptr, PSTRIDE_P);
  reduce4<<<2048, 256, 0, stream>>>(partials, res_p, (float*)d_out,
                                    (3072 * 2048) / 4, PSTRIDE_P);

  // 10) expert MLP: merged gate+up split-K4, fused gelu, down split-K8
  gemm_bt<4><<<dim3(64, 2, 4), 256, 0, stream>>>(h2_e, 1024, BIG, 0, 0, t_wgate_e, 1024,
                                                 pgu, 8192, 256, nullptr, nullptr, 0, 1, PSTRIDE_GU);
  fuse_gelu<<<1024, 256, 0, stream>>>(pgu, g_e, (256 * 4096) / 4, PSTRIDE_GU);
  gemm_bt<4><<<dim3(8, 2, 8), 256, 0, stream>>>(g_e, 4096, BIG, 0, 0, t_wdown_e, 4096,
                                                pd, 1024, 512, nullptr, nullptr, 0, 1, PSTRIDE_E);
  reduce_gated<<<256, 256, 0, stream>>>(pd, PSTRIDE_E, 8, res_e, mod2 + 2048, 3072, 64, 1024,
                                        (float*)d_out + (size_t)3072 * 2048, (256 * 1024) / 4);
}